// Round 1
// 162.461 us; speedup vs baseline: 1.0544x; 1.0544x over previous
//
#include <hip/hip_runtime.h>

// grid [2,160,160,160,3] fp32; interior 156^3 per batch.
#define OY 480                    // 160*3
#define OX 76800                  // 160*480
#define SB 12288000               // 160*76800
#define JT 12                    // interior j per block (13 tiles)
#define KT 39                    // interior k per block (4 tiles)
#define IT 13                    // interior i marched per block (12 segs)
#define NSEG 12                  // i segments
#define NBLK 1248                // 2 * 13 * 4 * 12
#define ROWF 129                  // floats per staged row: 43 z * 3 comps
#define RW 132                    // padded LDS row stride (floats)
#define NROW 16                   // JT + 4 halo rows
#define SLICE (NROW*RW)           // 2112 floats per slice buffer
#define NBUF 6                    // rolling slice buffers (1 barrier/step safe)
#define SLICE_FLOATS (NROW*ROWF)  // 2064 floats actually staged
#define PTS (JT*KT)               // 468 points per i-step
#define INV_SIZE (1.0f/22778496.0f)  // 2*156^3*3

// Block: 512 threads. Marches i over IT slices; per step stages one new
// (16 row x 129 float) slice into a 6-deep LDS ring and computes 468
// stencil points from the 5 center slices. Global data read once per
// block as dense dwords; stencil served from LDS.
// Occupancy note: LDS 50.7KB/block -> 3 blocks/CU resident; grid of 1248
// (4.9/CU queued) keeps all CUs at the LDS cap (~24 waves/CU) vs the old
// 416-block grid (1.6/CU, ~13 waves/CU, latency-bound at 28% occupancy).
__global__ __launch_bounds__(512)
void be_partials(const float* __restrict__ g, float* __restrict__ partial) {
    __shared__ float lds[NBUF * SLICE];
    __shared__ float wsum[8];

    const int tid = threadIdx.x;
    const int bid = blockIdx.x;
    const int kt   = bid & 3;
    const int rest = bid >> 2;         // 0..311
    const int is   = rest % NSEG;      // 0..11
    const int r    = rest / NSEG;      // 0..25
    const int jt   = r % 13;
    const int bb   = r / 13;

    const int j0  = jt * JT;           // global rows j0..j0+15
    const int k0z = kt * KT;           // global z k0z..k0z+42
    const int ib  = is * IT;           // global x slices ib..ib+IT+3

    const float* __restrict__ G = g + (size_t)bb * SB;

    // ---- fixed per-thread staging offsets (4 + optional tail) ----
    int gd0, gd1, gd2, gd3, gd4 = 0, ld0, ld1, ld2, ld3, ld4 = 0;
    {
        int f, row, pos;
        f = tid;        row = f / ROWF; pos = f - row * ROWF;
        gd0 = (j0 + row) * OY + k0z * 3 + pos;  ld0 = row * RW + pos;
        f = tid + 512;  row = f / ROWF; pos = f - row * ROWF;
        gd1 = (j0 + row) * OY + k0z * 3 + pos;  ld1 = row * RW + pos;
        f = tid + 1024; row = f / ROWF; pos = f - row * ROWF;
        gd2 = (j0 + row) * OY + k0z * 3 + pos;  ld2 = row * RW + pos;
        f = tid + 1536; row = f / ROWF; pos = f - row * ROWF;
        gd3 = (j0 + row) * OY + k0z * 3 + pos;  ld3 = row * RW + pos;
    }
    const bool tail = (tid < SLICE_FLOATS - 2048);   // 16 threads
    if (tail) {
        int f = tid + 2048; int row = f / ROWF; int pos = f - row * ROWF;
        gd4 = (j0 + row) * OY + k0z * 3 + pos;  ld4 = row * RW + pos;
    }

    // ---- compute-point mapping ----
    const bool act = tid < PTS;
    int jj = tid / KT;
    int kk = tid - jj * KT;
    if (!act) { jj = 0; kk = 0; }
    const int cbase = (jj + 2) * RW + (kk + 2) * 3;   // center comp0 (in-slice)

    // ---- warmup: stage slices ib..ib+4 ----
    #pragma unroll
    for (int w = 0; w < 5; ++w) {
        const int x = ib + w;
        const float* base = G + (size_t)x * OX;
        float a0 = base[gd0], a1 = base[gd1], a2 = base[gd2], a3 = base[gd3];
        float a4 = tail ? base[gd4] : 0.0f;
        float* L = lds + (x % NBUF) * SLICE;
        L[ld0] = a0; L[ld1] = a1; L[ld2] = a2; L[ld3] = a3;
        if (tail) L[ld4] = a4;
    }
    __syncthreads();

    float s = 0.0f;
    for (int i0 = ib; i0 < ib + IT; ++i0) {
        // 1) issue next slice's global loads (one step ahead of use)
        const int xn = i0 + 5;
        const bool doLoad = (xn <= ib + IT + 3);
        float a0 = 0.f, a1 = 0.f, a2 = 0.f, a3 = 0.f, a4 = 0.f;
        if (doLoad) {
            const float* base = G + (size_t)xn * OX;
            a0 = base[gd0]; a1 = base[gd1]; a2 = base[gd2]; a3 = base[gd3];
            if (tail) a4 = base[gd4];
        }

        // 2) compute current i0 from slices x = i0..i0+4 (buffers x%6)
        if (act) {
            int s0 = i0 % NBUF;
            int s1 = s0 + 1; if (s1 >= NBUF) s1 -= NBUF;
            int s2 = s1 + 1; if (s2 >= NBUF) s2 -= NBUF;
            int s3 = s2 + 1; if (s3 >= NBUF) s3 -= NBUF;
            int s4 = s3 + 1; if (s4 >= NBUF) s4 -= NBUF;
            const float* Sm2 = lds + s0 * SLICE + cbase;  // x = i0   (di=-2)
            const float* Sm1 = lds + s1 * SLICE + cbase;  // di=-1
            const float* Sc  = lds + s2 * SLICE + cbase;  // center
            const float* Sp1 = lds + s3 * SLICE + cbase;  // di=+1
            const float* Sp2 = lds + s4 * SLICE + cbase;  // di=+2

            const float c0 = Sc[0], c1 = Sc[1], c2 = Sc[2];
            float hzz0 = Sc[6] - 2.0f*c0 + Sc[-6];
            float hzz1 = Sc[7] - 2.0f*c1 + Sc[-5];
            float hzz2 = Sc[8] - 2.0f*c2 + Sc[-4];
            float hyy0 = Sc[ 2*RW]     - 2.0f*c0 + Sc[-2*RW];
            float hyy1 = Sc[ 2*RW + 1] - 2.0f*c1 + Sc[-2*RW + 1];
            float hxx0 = Sp2[0] - 2.0f*c0 + Sm2[0];
            float hyz0 = (Sc[RW+3] - Sc[RW-3]) - (Sc[-RW+3] - Sc[-RW-3]);
            float hyz1 = (Sc[RW+4] - Sc[RW-2]) - (Sc[-RW+4] - Sc[-RW-2]);
            float hyz2 = (Sc[RW+5] - Sc[RW-1]) - (Sc[-RW+5] - Sc[-RW-1]);
            float hxy0 = (Sp1[ RW]   - Sp1[-RW])   - (Sm1[ RW]   - Sm1[-RW]);
            float hxy1 = (Sp1[ RW+1] - Sp1[-RW+1]) - (Sm1[ RW+1] - Sm1[-RW+1]);
            float hxz0 = (Sp1[3] - Sp1[-3]) - (Sm1[3] - Sm1[-3]);
            float hxz1 = (Sp1[4] - Sp1[-2]) - (Sm1[4] - Sm1[-2]);
            float hxz2 = (Sp1[5] - Sp1[-1]) - (Sm1[5] - Sm1[-1]);

            // weight classes (multiplicity * 0.0625 folded at the end)
            float w1 = hxx0*hxx0;
            w1 = fmaf(hyy1, hyy1, w1); w1 = fmaf(hzz2, hzz2, w1);
            w1 = fmaf(hxy1, hxy1, w1); w1 = fmaf(hxz2, hxz2, w1);
            w1 = fmaf(hyz2, hyz2, w1);
            float w2 = hyy0*hyy0;
            w2 = fmaf(hzz0, hzz0, w2); w2 = fmaf(hzz1, hzz1, w2);
            w2 = fmaf(hxz1, hxz1, w2);
            float w3 = hxy0*hxy0;
            w3 = fmaf(hxz0, hxz0, w3); w3 = fmaf(hyz1, hyz1, w3);
            float w4 = hyz0*hyz0;

            float t = fmaf(2.0f, w2, w1);
            t = fmaf(3.0f, w3, t);
            t = fmaf(4.0f, w4, t);
            s = fmaf(0.0625f, t, s);
        }

        // 3) retire staged slice into ring buffer (xn%6 not read this step)
        if (doLoad) {
            float* L = lds + (xn % NBUF) * SLICE;
            L[ld0] = a0; L[ld1] = a1; L[ld2] = a2; L[ld3] = a3;
            if (tail) L[ld4] = a4;
        }
        __syncthreads();
    }

    // ---- block reduction ----
    #pragma unroll
    for (int off = 32; off > 0; off >>= 1) s += __shfl_down(s, off, 64);
    if ((tid & 63) == 0) wsum[tid >> 6] = s;
    __syncthreads();
    if (tid == 0) {
        float tot = 0.0f;
        #pragma unroll
        for (int w = 0; w < 8; ++w) tot += wsum[w];
        partial[bid] = tot;
    }
}

__global__ __launch_bounds__(256)
void be_final(const float* __restrict__ partial, float* __restrict__ out) {
    float s = 0.0f;
    for (int i = threadIdx.x; i < NBLK; i += 256) s += partial[i];
    #pragma unroll
    for (int off = 32; off > 0; off >>= 1) s += __shfl_down(s, off, 64);
    __shared__ float ws[4];
    if ((threadIdx.x & 63) == 0) ws[threadIdx.x >> 6] = s;
    __syncthreads();
    if (threadIdx.x == 0)
        out[0] = ((ws[0] + ws[1]) + (ws[2] + ws[3])) * INV_SIZE;
}

extern "C" void kernel_launch(void* const* d_in, const int* in_sizes, int n_in,
                              void* d_out, int out_size, void* d_ws, size_t ws_size,
                              hipStream_t stream) {
    const float* grid = (const float*)d_in[0];
    float* out = (float*)d_out;
    float* partials = (float*)d_ws;    // 1248 floats

    be_partials<<<dim3(NBLK), dim3(512), 0, stream>>>(grid, partials);
    be_final<<<1, 256, 0, stream>>>(partials, out);
}